// Round 7
// baseline (273.190 us; speedup 1.0000x reference)
//
#include <hip/hip_runtime.h>
#include <hip/hip_bf16.h>

#define SEQ 1024
#define NH 8
#define HD 64
#define HID 512
#define BATCH 32
#define LOG2E 1.44269504f
#define PST 72              // p_lds row stride (f16): 144 B, 16B-aligned, bank-even

typedef _Float16 f16;
typedef f16 f16x4 __attribute__((ext_vector_type(4)));
typedef f16 f16x8 __attribute__((ext_vector_type(8)));
typedef float f32x4 __attribute__((ext_vector_type(4)));
typedef __fp16 h16x2 __attribute__((ext_vector_type(2)));

#define MFMA16 __builtin_amdgcn_mfma_f32_16x16x32_f16
#define EXP2F  __builtin_amdgcn_exp2f

// ---------------------------------------------------------------------------
// Kernel 1: transpose weights to f16, k-contiguous (B-operand layout)
// ---------------------------------------------------------------------------
__global__ __launch_bounds__(256) void transpose_w(const float* __restrict__ wq,
                                                   const float* __restrict__ wp,
                                                   f16* __restrict__ wTq,
                                                   f16* __restrict__ wTp) {
    int flat = blockIdx.x * 256 + threadIdx.x;
    if (flat < 64 * 1536) {
        int e = flat / 1536, j = flat % 1536;
        wTq[(size_t)j * 64 + e] = (f16)wq[flat];
    } else {
        int f2 = flat - 64 * 1536;
        int k = f2 / 64, n = f2 % 64;
        wTp[(size_t)n * 512 + k] = (f16)wp[f2];
    }
}

// ---------------------------------------------------------------------------
// Kernel 2: QKV projection (MFMA) + LDS-bounce coalesced stores. (unchanged)
//   Qb[bh][n][d] (pre-scaled by log2e), Kb[bh][n][d], Vtb[bh][d][n]
// ---------------------------------------------------------------------------
__global__ __launch_bounds__(256) void qkv_kernel(const float* __restrict__ x,
                                                  const f16* __restrict__ wTq,
                                                  const float* __restrict__ b_qkv,
                                                  f16* __restrict__ Qb,
                                                  f16* __restrict__ Kb,
                                                  f16* __restrict__ Vtb) {
    __shared__ __align__(16) char smem[36864];
    f16* xs = (f16*)smem;                  // [64][72]
    f16* wsh = (f16*)(smem + 9216);        // [192][72]
    f16* outs = (f16*)smem;                // [3][64][72]

    const int n0   = blockIdx.x * 64;
    const int y    = blockIdx.y;
    const int b    = y & 31, h = y >> 5;
    const int bh   = b * NH + h;
    const int tid  = threadIdx.x;
    const int wave = tid >> 6, lane = tid & 63;
    const int quad = lane >> 4, l16 = lane & 15;

    for (int p = 0; p < 2; p++) {
        int t = tid + p * 256;
        int row = t >> 3, col = (t & 7) * 8;
        const float* src = x + ((size_t)(b * SEQ + n0 + row)) * 64 + col;
        float4 a0 = *(const float4*)src;
        float4 a1 = *(const float4*)(src + 4);
        f16x8 v = {(f16)a0.x, (f16)a0.y, (f16)a0.z, (f16)a0.w,
                   (f16)a1.x, (f16)a1.y, (f16)a1.z, (f16)a1.w};
        *(f16x8*)(&xs[row * 72 + col]) = v;
    }
    for (int p = 0; p < 6; p++) {
        int row = p * 32 + (tid >> 3), col = (tid & 7) * 8;
        *(f16x8*)(&wsh[row * 72 + col]) =
            *(const f16x8*)(wTq + (size_t)(h * 192 + row) * 64 + col);
    }
    __syncthreads();

    f16x8 af[2];
    af[0] = *(const f16x8*)(&xs[(wave * 16 + l16) * 72 + quad * 8]);
    af[1] = *(const f16x8*)(&xs[(wave * 16 + l16) * 72 + quad * 8 + 32]);

    f32x4 acc[12];
    f32x4 z = {0.f, 0.f, 0.f, 0.f};
    for (int jt = 0; jt < 12; jt++) acc[jt] = z;
    for (int jt = 0; jt < 12; jt++)
        for (int ss = 0; ss < 2; ss++) {
            f16x8 bf = *(const f16x8*)(&wsh[(jt * 16 + l16) * 72 + quad * 8 + ss * 32]);
            acc[jt] = MFMA16(af[ss], bf, acc[jt], 0, 0, 0);
        }

    __syncthreads();   // done reading xs/wsh; reuse as outs

    for (int jt = 0; jt < 12; jt++) {
        int jl = jt * 16 + l16;
        float bias = b_qkv[h * 192 + jl];
        int d = jl / 3, c = jl - 3 * d;
        float scl = (c == 0) ? LOG2E : 1.0f;
        for (int r = 0; r < 4; r++) {
            int nl = wave * 16 + quad * 4 + r;
            int off = (c < 2) ? (c * 4608 + nl * 72 + d) : (2 * 4608 + d * 72 + nl);
            outs[off] = (f16)((acc[jt][r] + bias) * scl);
        }
    }
    __syncthreads();

    {
        int rr = tid >> 2, ch = (tid & 3) * 16;
        f16x8 v0, v1;
        v0 = *(const f16x8*)(&outs[rr * 72 + ch]);
        v1 = *(const f16x8*)(&outs[rr * 72 + ch + 8]);
        f16* qd = Qb + ((size_t)bh * SEQ + n0 + rr) * HD + ch;
        *(f16x8*)qd = v0; *(f16x8*)(qd + 8) = v1;
        v0 = *(const f16x8*)(&outs[4608 + rr * 72 + ch]);
        v1 = *(const f16x8*)(&outs[4608 + rr * 72 + ch + 8]);
        f16* kd = Kb + ((size_t)bh * SEQ + n0 + rr) * HD + ch;
        *(f16x8*)kd = v0; *(f16x8*)(kd + 8) = v1;
        v0 = *(const f16x8*)(&outs[9216 + rr * 72 + ch]);
        v1 = *(const f16x8*)(&outs[9216 + rr * 72 + ch + 8]);
        f16* vd = Vtb + ((size_t)bh * HD + rr) * SEQ + n0 + ch;
        *(f16x8*)vd = v0; *(f16x8*)(vd + 8) = v1;
    }
}

// ---------------------------------------------------------------------------
// Kernel 3: flash attention, 64 qrows/wave (256/block).
//   K/V staged via global_load_lds (width 16) into unpadded rows with a
//   16B-chunk XOR swizzle: physical chunk = chunk ^ (row&7). All fragment
//   reads are single b128 ops, exactly bank-even. Single buffer, 2 barriers
//   per kt (m97 pattern). P^T round-trips per-wave p_lds (stride 72,
//   b64 write / b128 read, bank-even). Softmax per-lane state in exp2 domain.
// Grid: 1024 blocks, XCD-swizzled (qt-siblings of a bh share id%8 -> L2 reuse).
// ---------------------------------------------------------------------------
__global__ __launch_bounds__(256) void flash_kernel(const f16* __restrict__ Qb,
                                                    const f16* __restrict__ Kb,
                                                    const f16* __restrict__ Vtb,
                                                    f16* __restrict__ attn) {
    __shared__ __align__(16) f16 kv[2][64 * 64];        // [K/V][row*64], XOR-chunked
    __shared__ __align__(16) f16 p_lds[4][4][16 * PST]; // [wave][j][qrow*PST]

    const int id   = blockIdx.x;
    const int xcd  = id & 7;
    const int kk   = id >> 3;
    const int qt   = kk & 3;
    const int bh   = ((kk >> 2) << 3) | xcd;
    const int b    = bh >> 3, h = bh & 7;
    const int tid  = threadIdx.x;
    const int wave = tid >> 6, lane = tid & 63;
    const int quad = lane >> 4, l16 = lane & 15;

    const f16* kg = Kb  + (size_t)bh * SEQ * HD;
    const f16* vg = Vtb + (size_t)bh * HD * SEQ;

    // staging geometry: each wave stages rows wave*16 .. wave*16+15 (2 insts)
    const int rr   = lane >> 3;             // 0..7 within 8-row group
    const int cc   = lane & 7;              // physical 16B chunk
    const int gcol = ((cc ^ rr) << 3);      // logical col (f16) for this chunk
    const int r0   = wave * 16 + rr;
    const int r1   = r0 + 8;
    f16* ldsK0 = &kv[0][(wave * 16 + 0) * 64] + lane * 8;
    f16* ldsK1 = &kv[0][(wave * 16 + 8) * 64] + lane * 8;
    f16* ldsV0 = &kv[1][(wave * 16 + 0) * 64] + lane * 8;
    f16* ldsV1 = &kv[1][(wave * 16 + 8) * 64] + lane * 8;

    // Q fragments (B-operand), 64 qrows: lane holds Q[qrow j*16+l16][d quad*8+..]
    const f16* Qp = Qb + ((size_t)bh * SEQ + qt * 256 + wave * 64) * HD;
    f16x8 qf[4][2];
    for (int j = 0; j < 4; j++)
        for (int ss = 0; ss < 2; ss++)
            qf[j][ss] = *(const f16x8*)(Qp + (size_t)(j * 16 + l16) * HD + ss * 32 + quad * 8);

    float m_st[4] = {-INFINITY, -INFINITY, -INFINITY, -INFINITY};
    float l_st[4] = {0.f, 0.f, 0.f, 0.f};
    f32x4 o[4][4];
    f32x4 z = {0.f, 0.f, 0.f, 0.f};
    for (int mt = 0; mt < 4; mt++)
        for (int j = 0; j < 4; j++) o[mt][j] = z;

    const int c_lo = ((quad ^ (l16 & 7)) << 3);          // phys col of logical chunk quad
    const int c_hi = (((quad + 4) ^ (l16 & 7)) << 3);    // phys col of logical chunk quad+4

    for (int kt = 0; kt < SEQ / 64; kt++) {
        __syncthreads();   // prior-iteration LDS reads complete before overwrite

        // async stage K/V tile kt (direct-to-LDS, XOR swizzle in global addr)
        {
            const f16* kgk = kg + (size_t)(kt * 64) * HD;
            const f16* vgk = vg + kt * 64;
            __builtin_amdgcn_global_load_lds(kgk + (size_t)r0 * HD + gcol, ldsK0, 16, 0, 0);
            __builtin_amdgcn_global_load_lds(kgk + (size_t)r1 * HD + gcol, ldsK1, 16, 0, 0);
            __builtin_amdgcn_global_load_lds(vgk + (size_t)r0 * SEQ + gcol, ldsV0, 16, 0, 0);
            __builtin_amdgcn_global_load_lds(vgk + (size_t)r1 * SEQ + gcol, ldsV1, 16, 0, 0);
        }
        __syncthreads();   // vmcnt(0) drained by barrier: tile visible

        // K fragments (b128, conflict-free)
        f16x8 ka[4], kc[4];
        for (int ct = 0; ct < 4; ct++) {
            const f16* kr = &kv[0][(ct * 16 + l16) * 64];
            ka[ct] = *(const f16x8*)(kr + c_lo);
            kc[ct] = *(const f16x8*)(kr + c_hi);
        }

        // S^T = K · Q^T + online softmax, qrow-pairs to bound registers
        for (int jp = 0; jp < 2; jp++) {
            f32x4 s[4][2];
            for (int ct = 0; ct < 4; ct++) {
                s[ct][0] = MFMA16(ka[ct], qf[jp * 2][0], z, 0, 0, 0);
                s[ct][0] = MFMA16(kc[ct], qf[jp * 2][1], s[ct][0], 0, 0, 0);
                s[ct][1] = MFMA16(ka[ct], qf[jp * 2 + 1][0], z, 0, 0, 0);
                s[ct][1] = MFMA16(kc[ct], qf[jp * 2 + 1][1], s[ct][1], 0, 0, 0);
            }
            for (int jj = 0; jj < 2; jj++) {
                const int j = jp * 2 + jj;
                float mx = fmaxf(fmaxf(fmaxf(s[0][jj][0], s[0][jj][1]), fmaxf(s[0][jj][2], s[0][jj][3])),
                                 fmaxf(fmaxf(s[1][jj][0], s[1][jj][1]), fmaxf(s[1][jj][2], s[1][jj][3])));
                mx = fmaxf(mx, fmaxf(fmaxf(fmaxf(s[2][jj][0], s[2][jj][1]), fmaxf(s[2][jj][2], s[2][jj][3])),
                                     fmaxf(fmaxf(s[3][jj][0], s[3][jj][1]), fmaxf(s[3][jj][2], s[3][jj][3]))));
                mx = fmaxf(mx, __shfl_xor(mx, 16, 64));
                mx = fmaxf(mx, __shfl_xor(mx, 32, 64));
                float mn = fmaxf(m_st[j], mx);
                float al = EXP2F(m_st[j] - mn);
                m_st[j] = mn;
                float rs = 0.f;
                for (int ct = 0; ct < 4; ct++)
                    for (int r = 0; r < 4; r++) {
                        float p = EXP2F(s[ct][jj][r] - mn);
                        s[ct][jj][r] = p;
                        rs += p;
                    }
                rs += __shfl_xor(rs, 16, 64);
                rs += __shfl_xor(rs, 32, 64);
                l_st[j] = l_st[j] * al + rs;
                for (int mt = 0; mt < 4; mt++) o[mt][j] *= al;

                // P^T -> per-wave LDS (packed cvt, b64 writes, bank-even)
                for (int ct = 0; ct < 4; ct++) {
                    h16x2 lo = __builtin_amdgcn_cvt_pkrtz(s[ct][jj][0], s[ct][jj][1]);
                    h16x2 hi = __builtin_amdgcn_cvt_pkrtz(s[ct][jj][2], s[ct][jj][3]);
                    uint2 w = {__builtin_bit_cast(unsigned int, lo),
                               __builtin_bit_cast(unsigned int, hi)};
                    *(uint2*)(&p_lds[wave][j][l16 * PST + ct * 16 + quad * 4]) = w;
                }
            }
        }

        __asm__ volatile("s_waitcnt lgkmcnt(0)" ::: "memory");

        // O^T += V^T · P^T  (b128 reads all around)
        for (int c2 = 0; c2 < 2; c2++) {
            f16x8 va[4];
            for (int mt = 0; mt < 4; mt++) {
                const int pc = (((c2 * 4 + quad) ^ (l16 & 7)) << 3);
                va[mt] = *(const f16x8*)(&kv[1][(mt * 16 + l16) * 64] + pc);
            }
            for (int j = 0; j < 4; j++) {
                f16x8 pj = *(const f16x8*)(&p_lds[wave][j][l16 * PST + c2 * 32 + quad * 8]);
                for (int mt = 0; mt < 4; mt++)
                    o[mt][j] = MFMA16(va[mt], pj, o[mt][j], 0, 0, 0);
            }
        }
    }

    // epilogue: attn[b][n][h*64+d], post-softmax /8 folded in
    for (int j = 0; j < 4; j++) {
        float sc = 1.0f / (8.0f * l_st[j]);
        int n = qt * 256 + wave * 64 + j * 16 + l16;
        f16* op = attn + ((size_t)b * SEQ + n) * HID + h * HD + quad * 4;
        for (int mt = 0; mt < 4; mt++) {
            f16x4 w = {(f16)(o[mt][j][0] * sc), (f16)(o[mt][j][1] * sc),
                       (f16)(o[mt][j][2] * sc), (f16)(o[mt][j][3] * sc)};
            *(f16x4*)(op + mt * 16) = w;
        }
    }
}

// ---------------------------------------------------------------------------
// Kernel 4: output projection. attn (32768 x 512) @ w_proj (512 x 64) + b.
// ---------------------------------------------------------------------------
__global__ __launch_bounds__(256) void proj_kernel(const f16* __restrict__ attn,
                                                   const f16* __restrict__ wTp,
                                                   const float* __restrict__ b_proj,
                                                   float* __restrict__ out) {
    __shared__ __align__(16) f16 a_lds[64][72];
    __shared__ __align__(16) f16 w_lds[64][72];

    const int blk  = blockIdx.x;
    const int tid  = threadIdx.x;
    const int wave = tid >> 6, lane = tid & 63;
    const int quad = lane >> 4, l16 = lane & 15;

    f32x4 acc[4];
    f32x4 z = {0.f, 0.f, 0.f, 0.f};
    for (int ct = 0; ct < 4; ct++) acc[ct] = z;

    for (int kt = 0; kt < 8; kt++) {
        __syncthreads();
        for (int p = 0; p < 2; p++) {
            int t = tid + p * 256;
            int row = t >> 3, col = (t & 7) * 8;
            *(f16x8*)(&a_lds[row][col]) =
                *(const f16x8*)(attn + ((size_t)(blk * 64 + row)) * HID + kt * 64 + col);
            *(f16x8*)(&w_lds[row][col]) =
                *(const f16x8*)(wTp + (size_t)row * HID + kt * 64 + col);
        }
        __syncthreads();
        for (int ss = 0; ss < 2; ss++) {
            f16x8 af = *(const f16x8*)(&a_lds[wave * 16 + l16][quad * 8 + ss * 32]);
            for (int ct = 0; ct < 4; ct++) {
                f16x8 bf = *(const f16x8*)(&w_lds[ct * 16 + l16][quad * 8 + ss * 32]);
                acc[ct] = MFMA16(af, bf, acc[ct], 0, 0, 0);
            }
        }
    }

    for (int ct = 0; ct < 4; ct++) {
        float bias = b_proj[ct * 16 + l16];
        for (int r = 0; r < 4; r++) {
            int row = blk * 64 + wave * 16 + quad * 4 + r;
            out[(size_t)row * HD + ct * 16 + l16] = acc[ct][r] + bias;
        }
    }
}

// ---------------------------------------------------------------------------
extern "C" void kernel_launch(void* const* d_in, const int* in_sizes, int n_in,
                              void* d_out, int out_size, void* d_ws, size_t ws_size,
                              hipStream_t stream) {
    (void)in_sizes; (void)n_in; (void)out_size; (void)ws_size;
    const float* x      = (const float*)d_in[0];
    const float* w_qkv  = (const float*)d_in[1];
    const float* b_qkv  = (const float*)d_in[2];
    const float* w_proj = (const float*)d_in[3];
    const float* b_proj = (const float*)d_in[4];
    float* out = (float*)d_out;

    char* ws = (char*)d_ws;
    const size_t QKV_EL = (size_t)BATCH * NH * SEQ * HD;
    f16* wTq  = (f16*)(ws);
    f16* wTp  = (f16*)(ws + 196608);
    f16* Qb   = (f16*)(ws + 262144);
    f16* Kb   = (f16*)(ws + 262144 + 2 * QKV_EL);
    f16* Vtb  = (f16*)(ws + 262144 + 4 * QKV_EL);
    f16* attn = (f16*)(ws + 262144 + 6 * QKV_EL);

    transpose_w<<<512, 256, 0, stream>>>(w_qkv, w_proj, wTq, wTp);
    qkv_kernel<<<dim3(16, BATCH * NH), 256, 0, stream>>>(x, wTq, b_qkv, Qb, Kb, Vtb);
    flash_kernel<<<1024, 256, 0, stream>>>(Qb, Kb, Vtb, attn);
    proj_kernel<<<512, 256, 0, stream>>>(attn, wTp, b_proj, out);
}

// Round 8
// 235.172 us; speedup vs baseline: 1.1617x; 1.1617x over previous
//
#include <hip/hip_runtime.h>
#include <hip/hip_bf16.h>

#define SEQ 1024
#define NH 8
#define HD 64
#define HID 512
#define BATCH 32
#define LOG2E 1.44269504f
#define PST 72              // p_lds row stride (f16): 144 B, 16B-aligned, bank-even

typedef _Float16 f16;
typedef f16 f16x4 __attribute__((ext_vector_type(4)));
typedef f16 f16x8 __attribute__((ext_vector_type(8)));
typedef float f32x4 __attribute__((ext_vector_type(4)));
typedef __fp16 h16x2 __attribute__((ext_vector_type(2)));

#define MFMA16 __builtin_amdgcn_mfma_f32_16x16x32_f16
#define EXP2F  __builtin_amdgcn_exp2f

// ---------------------------------------------------------------------------
// Kernel 1: transpose weights to f16, k-contiguous.
// wTq column order remapped to (h, c, d): j' = h*192 + c*64 + d  where the
// original column is h*192 + d*3 + c  ->  qkv epilogue scatter becomes
// contiguous/conflict-free and needs no /3 %3.
// ---------------------------------------------------------------------------
__global__ __launch_bounds__(256) void transpose_w(const float* __restrict__ wq,
                                                   const float* __restrict__ wp,
                                                   f16* __restrict__ wTq,
                                                   f16* __restrict__ wTp) {
    int flat = blockIdx.x * 256 + threadIdx.x;
    if (flat < 64 * 1536) {
        int e = flat / 1536, col = flat % 1536;
        int h = col / 192, r = col - h * 192;
        int d = r / 3, c = r - 3 * d;
        int jp = h * 192 + c * 64 + d;
        wTq[(size_t)jp * 64 + e] = (f16)wq[flat];
    } else {
        int f2 = flat - 64 * 1536;
        int k = f2 / 64, n = f2 % 64;
        wTp[(size_t)n * 512 + k] = (f16)wp[f2];
    }
}

// ---------------------------------------------------------------------------
// Kernel 2: QKV projection (MFMA) + LDS-bounce coalesced stores.
// With (c,d)-grouped wTq: jt 0-3 -> Q, 4-7 -> K, 8-11 -> V.
// Q pre-scaled by log2(e) in fp32 (flash softmax runs in exp2 domain).
//   Qb[bh][n][d], Kb[bh][n][d], Vtb[bh][d][n]
// ---------------------------------------------------------------------------
__global__ __launch_bounds__(256) void qkv_kernel(const float* __restrict__ x,
                                                  const f16* __restrict__ wTq,
                                                  const float* __restrict__ b_qkv,
                                                  f16* __restrict__ Qb,
                                                  f16* __restrict__ Kb,
                                                  f16* __restrict__ Vtb) {
    __shared__ __align__(16) char smem[36864];
    f16* xs = (f16*)smem;                  // [64][72]
    f16* wsh = (f16*)(smem + 9216);        // [192][72]
    f16* outs = (f16*)smem;                // [3][64][72]

    const int n0   = blockIdx.x * 64;
    const int y    = blockIdx.y;
    const int b    = y & 31, h = y >> 5;
    const int bh   = b * NH + h;
    const int tid  = threadIdx.x;
    const int wave = tid >> 6, lane = tid & 63;
    const int quad = lane >> 4, l16 = lane & 15;

    for (int p = 0; p < 2; p++) {
        int t = tid + p * 256;
        int row = t >> 3, col = (t & 7) * 8;
        const float* src = x + ((size_t)(b * SEQ + n0 + row)) * 64 + col;
        float4 a0 = *(const float4*)src;
        float4 a1 = *(const float4*)(src + 4);
        f16x8 v = {(f16)a0.x, (f16)a0.y, (f16)a0.z, (f16)a0.w,
                   (f16)a1.x, (f16)a1.y, (f16)a1.z, (f16)a1.w};
        *(f16x8*)(&xs[row * 72 + col]) = v;
    }
    for (int p = 0; p < 6; p++) {
        int row = p * 32 + (tid >> 3), col = (tid & 7) * 8;
        *(f16x8*)(&wsh[row * 72 + col]) =
            *(const f16x8*)(wTq + (size_t)(h * 192 + row) * 64 + col);
    }
    __syncthreads();

    f16x8 af[2];
    af[0] = *(const f16x8*)(&xs[(wave * 16 + l16) * 72 + quad * 8]);
    af[1] = *(const f16x8*)(&xs[(wave * 16 + l16) * 72 + quad * 8 + 32]);

    f32x4 acc[12];
    f32x4 z = {0.f, 0.f, 0.f, 0.f};
    for (int jt = 0; jt < 12; jt++) acc[jt] = z;
    for (int jt = 0; jt < 12; jt++)
        for (int ss = 0; ss < 2; ss++) {
            f16x8 bf = *(const f16x8*)(&wsh[(jt * 16 + l16) * 72 + quad * 8 + ss * 32]);
            acc[jt] = MFMA16(af[ss], bf, acc[jt], 0, 0, 0);
        }

    __syncthreads();   // done reading xs/wsh; reuse as outs

    for (int jt = 0; jt < 12; jt++) {
        int c = jt >> 2, d = (jt & 3) * 16 + l16;
        float bias = b_qkv[h * 192 + d * 3 + c];
        float scl = (c == 0) ? LOG2E : 1.0f;
        for (int r = 0; r < 4; r++) {
            int nl = wave * 16 + quad * 4 + r;
            int off = (c < 2) ? (c * 4608 + nl * 72 + d) : (9216 + d * 72 + nl);
            outs[off] = (f16)((acc[jt][r] + bias) * scl);
        }
    }
    __syncthreads();

    {
        int rr = tid >> 2, ch = (tid & 3) * 16;
        f16x8 v0, v1;
        v0 = *(const f16x8*)(&outs[rr * 72 + ch]);
        v1 = *(const f16x8*)(&outs[rr * 72 + ch + 8]);
        f16* qd = Qb + ((size_t)bh * SEQ + n0 + rr) * HD + ch;
        *(f16x8*)qd = v0; *(f16x8*)(qd + 8) = v1;
        v0 = *(const f16x8*)(&outs[4608 + rr * 72 + ch]);
        v1 = *(const f16x8*)(&outs[4608 + rr * 72 + ch + 8]);
        f16* kd = Kb + ((size_t)bh * SEQ + n0 + rr) * HD + ch;
        *(f16x8*)kd = v0; *(f16x8*)(kd + 8) = v1;
        v0 = *(const f16x8*)(&outs[9216 + rr * 72 + ch]);
        v1 = *(const f16x8*)(&outs[9216 + rr * 72 + ch + 8]);
        f16* vd = Vtb + ((size_t)bh * HD + rr) * SEQ + n0 + ch;
        *(f16x8*)vd = v0; *(f16x8*)(vd + 8) = v1;
    }
}

// ---------------------------------------------------------------------------
// Kernel 3: flash attention, 64 qrows/wave, 3 blocks/CU.
//   K/V staged via global_load_lds (width 16), XOR-16B-chunk swizzle.
//   ka cached in regs; kc streamed per jp (register-budget: stay under the
//   170-VGPR cliff -> __launch_bounds__(256,3)).
//   Ballot-gated o-rescale skips ~75% of alpha multiplies.
// Grid: 1024 blocks, XCD-swizzled (qt-siblings of a bh share id%8).
// ---------------------------------------------------------------------------
__global__ __launch_bounds__(256, 3) void flash_kernel(const f16* __restrict__ Qb,
                                                       const f16* __restrict__ Kb,
                                                       const f16* __restrict__ Vtb,
                                                       f16* __restrict__ attn) {
    __shared__ __align__(16) f16 kv[2][64 * 64];        // [K/V][row*64], XOR-chunked
    __shared__ __align__(16) f16 p_lds[4][4][16 * PST]; // [wave][j][qrow*PST]

    const int id   = blockIdx.x;
    const int xcd  = id & 7;
    const int kk   = id >> 3;
    const int qt   = kk & 3;
    const int bh   = ((kk >> 2) << 3) | xcd;
    const int b    = bh >> 3, h = bh & 7;
    const int tid  = threadIdx.x;
    const int wave = tid >> 6, lane = tid & 63;
    const int quad = lane >> 4, l16 = lane & 15;

    const f16* kg = Kb  + (size_t)bh * SEQ * HD;
    const f16* vg = Vtb + (size_t)bh * HD * SEQ;

    // staging geometry: each wave stages 16 rows of K and 16 of V (4 DMA insts)
    const int rr   = lane >> 3;             // 0..7 row within 8-row group
    const int cc   = lane & 7;              // physical 16B chunk
    const int gcol = ((cc ^ rr) << 3);      // logical col (f16) for this chunk
    const int r0   = wave * 16 + rr;
    const int r1   = r0 + 8;
    f16* ldsK0 = &kv[0][(wave * 16 + 0) * 64] + lane * 8;
    f16* ldsK1 = &kv[0][(wave * 16 + 8) * 64] + lane * 8;
    f16* ldsV0 = &kv[1][(wave * 16 + 0) * 64] + lane * 8;
    f16* ldsV1 = &kv[1][(wave * 16 + 8) * 64] + lane * 8;

    // Q fragments (B-operand), 64 qrows/wave
    const f16* Qp = Qb + ((size_t)bh * SEQ + qt * 256 + wave * 64) * HD;
    f16x8 qf[4][2];
    for (int j = 0; j < 4; j++)
        for (int ss = 0; ss < 2; ss++)
            qf[j][ss] = *(const f16x8*)(Qp + (size_t)(j * 16 + l16) * HD + ss * 32 + quad * 8);

    float m_st[4] = {-INFINITY, -INFINITY, -INFINITY, -INFINITY};
    float l_st[4] = {0.f, 0.f, 0.f, 0.f};
    f32x4 o[4][4];
    f32x4 z = {0.f, 0.f, 0.f, 0.f};
    for (int mt = 0; mt < 4; mt++)
        for (int j = 0; j < 4; j++) o[mt][j] = z;

    const int c_lo = ((quad ^ (l16 & 7)) << 3);          // phys col of logical chunk quad
    const int c_hi = (((quad + 4) ^ (l16 & 7)) << 3);    // phys col of logical chunk quad+4

    for (int kt = 0; kt < SEQ / 64; kt++) {
        __syncthreads();   // prior-iteration LDS reads complete before overwrite

        {
            const f16* kgk = kg + (size_t)(kt * 64) * HD;
            const f16* vgk = vg + kt * 64;
            __builtin_amdgcn_global_load_lds(kgk + (size_t)r0 * HD + gcol, ldsK0, 16, 0, 0);
            __builtin_amdgcn_global_load_lds(kgk + (size_t)r1 * HD + gcol, ldsK1, 16, 0, 0);
            __builtin_amdgcn_global_load_lds(vgk + (size_t)r0 * SEQ + gcol, ldsV0, 16, 0, 0);
            __builtin_amdgcn_global_load_lds(vgk + (size_t)r1 * SEQ + gcol, ldsV1, 16, 0, 0);
        }
        __syncthreads();   // barrier drains vmcnt: tile visible

        // K low-half fragments cached; high-half streamed per jp
        f16x8 ka[4];
        for (int ct = 0; ct < 4; ct++)
            ka[ct] = *(const f16x8*)(&kv[0][(ct * 16 + l16) * 64] + c_lo);

        for (int jp = 0; jp < 2; jp++) {
            f32x4 s[4][2];
            for (int ct = 0; ct < 4; ct++) {
                f16x8 kc = *(const f16x8*)(&kv[0][(ct * 16 + l16) * 64] + c_hi);
                s[ct][0] = MFMA16(ka[ct], qf[jp * 2][0], z, 0, 0, 0);
                s[ct][0] = MFMA16(kc, qf[jp * 2][1], s[ct][0], 0, 0, 0);
                s[ct][1] = MFMA16(ka[ct], qf[jp * 2 + 1][0], z, 0, 0, 0);
                s[ct][1] = MFMA16(kc, qf[jp * 2 + 1][1], s[ct][1], 0, 0, 0);
            }
            for (int jj = 0; jj < 2; jj++) {
                const int j = jp * 2 + jj;
                float mx = fmaxf(fmaxf(fmaxf(s[0][jj][0], s[0][jj][1]), fmaxf(s[0][jj][2], s[0][jj][3])),
                                 fmaxf(fmaxf(s[1][jj][0], s[1][jj][1]), fmaxf(s[1][jj][2], s[1][jj][3])));
                mx = fmaxf(mx, fmaxf(fmaxf(fmaxf(s[2][jj][0], s[2][jj][1]), fmaxf(s[2][jj][2], s[2][jj][3])),
                                     fmaxf(fmaxf(s[3][jj][0], s[3][jj][1]), fmaxf(s[3][jj][2], s[3][jj][3]))));
                mx = fmaxf(mx, __shfl_xor(mx, 16, 64));
                mx = fmaxf(mx, __shfl_xor(mx, 32, 64));
                float mn = fmaxf(m_st[j], mx);
                float al = EXP2F(m_st[j] - mn);
                m_st[j] = mn;
                float rs = 0.f;
                for (int ct = 0; ct < 4; ct++)
                    for (int r = 0; r < 4; r++) {
                        float p = EXP2F(s[ct][jj][r] - mn);
                        s[ct][jj][r] = p;
                        rs += p;
                    }
                rs += __shfl_xor(rs, 16, 64);
                rs += __shfl_xor(rs, 32, 64);
                l_st[j] = l_st[j] * al + rs;
                if (!__all(al >= 1.0f))                 // wave-uniform skip
                    for (int mt = 0; mt < 4; mt++) o[mt][j] *= al;

                for (int ct = 0; ct < 4; ct++) {
                    h16x2 lo = __builtin_amdgcn_cvt_pkrtz(s[ct][jj][0], s[ct][jj][1]);
                    h16x2 hi = __builtin_amdgcn_cvt_pkrtz(s[ct][jj][2], s[ct][jj][3]);
                    uint2 w = {__builtin_bit_cast(unsigned int, lo),
                               __builtin_bit_cast(unsigned int, hi)};
                    *(uint2*)(&p_lds[wave][j][l16 * PST + ct * 16 + quad * 4]) = w;
                }
            }
        }

        __asm__ volatile("s_waitcnt lgkmcnt(0)" ::: "memory");

        // O^T += V^T · P^T
        for (int c2 = 0; c2 < 2; c2++) {
            f16x8 va[4];
            for (int mt = 0; mt < 4; mt++) {
                const int pc = (((c2 * 4 + quad) ^ (l16 & 7)) << 3);
                va[mt] = *(const f16x8*)(&kv[1][(mt * 16 + l16) * 64] + pc);
            }
            for (int j = 0; j < 4; j++) {
                f16x8 pj = *(const f16x8*)(&p_lds[wave][j][l16 * PST + c2 * 32 + quad * 8]);
                for (int mt = 0; mt < 4; mt++)
                    o[mt][j] = MFMA16(va[mt], pj, o[mt][j], 0, 0, 0);
            }
        }
    }

    // epilogue: attn[b][n][h*64+d], post-softmax /8 folded in
    for (int j = 0; j < 4; j++) {
        float sc = 1.0f / (8.0f * l_st[j]);
        int n = qt * 256 + wave * 64 + j * 16 + l16;
        f16* op = attn + ((size_t)b * SEQ + n) * HID + h * HD + quad * 4;
        for (int mt = 0; mt < 4; mt++) {
            f16x4 w = {(f16)(o[mt][j][0] * sc), (f16)(o[mt][j][1] * sc),
                       (f16)(o[mt][j][2] * sc), (f16)(o[mt][j][3] * sc)};
            *(f16x4*)(op + mt * 16) = w;
        }
    }
}

// ---------------------------------------------------------------------------
// Kernel 4: output projection. attn (32768 x 512) @ w_proj (512 x 64) + b.
// ---------------------------------------------------------------------------
__global__ __launch_bounds__(256) void proj_kernel(const f16* __restrict__ attn,
                                                   const f16* __restrict__ wTp,
                                                   const float* __restrict__ b_proj,
                                                   float* __restrict__ out) {
    __shared__ __align__(16) f16 a_lds[64][72];
    __shared__ __align__(16) f16 w_lds[64][72];

    const int blk  = blockIdx.x;
    const int tid  = threadIdx.x;
    const int wave = tid >> 6, lane = tid & 63;
    const int quad = lane >> 4, l16 = lane & 15;

    f32x4 acc[4];
    f32x4 z = {0.f, 0.f, 0.f, 0.f};
    for (int ct = 0; ct < 4; ct++) acc[ct] = z;

    for (int kt = 0; kt < 8; kt++) {
        __syncthreads();
        for (int p = 0; p < 2; p++) {
            int t = tid + p * 256;
            int row = t >> 3, col = (t & 7) * 8;
            *(f16x8*)(&a_lds[row][col]) =
                *(const f16x8*)(attn + ((size_t)(blk * 64 + row)) * HID + kt * 64 + col);
            *(f16x8*)(&w_lds[row][col]) =
                *(const f16x8*)(wTp + (size_t)row * HID + kt * 64 + col);
        }
        __syncthreads();
        for (int ss = 0; ss < 2; ss++) {
            f16x8 af = *(const f16x8*)(&a_lds[wave * 16 + l16][quad * 8 + ss * 32]);
            for (int ct = 0; ct < 4; ct++) {
                f16x8 bf = *(const f16x8*)(&w_lds[ct * 16 + l16][quad * 8 + ss * 32]);
                acc[ct] = MFMA16(af, bf, acc[ct], 0, 0, 0);
            }
        }
    }

    for (int ct = 0; ct < 4; ct++) {
        float bias = b_proj[ct * 16 + l16];
        for (int r = 0; r < 4; r++) {
            int row = blk * 64 + wave * 16 + quad * 4 + r;
            out[(size_t)row * HD + ct * 16 + l16] = acc[ct][r] + bias;
        }
    }
}

// ---------------------------------------------------------------------------
extern "C" void kernel_launch(void* const* d_in, const int* in_sizes, int n_in,
                              void* d_out, int out_size, void* d_ws, size_t ws_size,
                              hipStream_t stream) {
    (void)in_sizes; (void)n_in; (void)out_size; (void)ws_size;
    const float* x      = (const float*)d_in[0];
    const float* w_qkv  = (const float*)d_in[1];
    const float* b_qkv  = (const float*)d_in[2];
    const float* w_proj = (const float*)d_in[3];
    const float* b_proj = (const float*)d_in[4];
    float* out = (float*)d_out;

    char* ws = (char*)d_ws;
    const size_t QKV_EL = (size_t)BATCH * NH * SEQ * HD;
    f16* wTq  = (f16*)(ws);
    f16* wTp  = (f16*)(ws + 196608);
    f16* Qb   = (f16*)(ws + 262144);
    f16* Kb   = (f16*)(ws + 262144 + 2 * QKV_EL);
    f16* Vtb  = (f16*)(ws + 262144 + 4 * QKV_EL);
    f16* attn = (f16*)(ws + 262144 + 6 * QKV_EL);

    transpose_w<<<512, 256, 0, stream>>>(w_qkv, w_proj, wTq, wTp);
    qkv_kernel<<<dim3(16, BATCH * NH), 256, 0, stream>>>(x, wTq, b_qkv, Qb, Kb, Vtb);
    flash_kernel<<<1024, 256, 0, stream>>>(Qb, Kb, Vtb, attn);
    proj_kernel<<<512, 256, 0, stream>>>(attn, wTp, b_proj, out);
}

// Round 9
// 212.469 us; speedup vs baseline: 1.2858x; 1.1069x over previous
//
#include <hip/hip_runtime.h>
#include <hip/hip_bf16.h>

#define SEQ 1024
#define NH 8
#define HD 64
#define HID 512
#define BATCH 32
#define LOG2E 1.44269504f
#define KST 68              // LDS row stride (f16): b64 ops bank-balanced, 0 conflicts (R6-measured)

typedef _Float16 f16;
typedef f16 f16x4 __attribute__((ext_vector_type(4)));
typedef f16 f16x8 __attribute__((ext_vector_type(8)));
typedef float f32x4 __attribute__((ext_vector_type(4)));
typedef __fp16 h16x2 __attribute__((ext_vector_type(2)));

#define MFMA16 __builtin_amdgcn_mfma_f32_16x16x32_f16
#define EXP2F  __builtin_amdgcn_exp2f

// 8B-granular LDS load/store (rows 8B-aligned at stride 68)
__device__ __forceinline__ f16x8 ld8(const f16* p) {
    f16x4 a = *(const f16x4*)p;
    f16x4 b = *(const f16x4*)(p + 4);
    return __builtin_shufflevector(a, b, 0, 1, 2, 3, 4, 5, 6, 7);
}
__device__ __forceinline__ void st8(f16* p, f16x8 v) {
    *(f16x4*)p       = __builtin_shufflevector(v, v, 0, 1, 2, 3);
    *(f16x4*)(p + 4) = __builtin_shufflevector(v, v, 4, 5, 6, 7);
}

// ---------------------------------------------------------------------------
// Kernel 1: transpose weights to f16, k-contiguous. wTq columns remapped to
// (h, c, d) so qkv's epilogue scatter is contiguous (no /3 %3).
// ---------------------------------------------------------------------------
__global__ __launch_bounds__(256) void transpose_w(const float* __restrict__ wq,
                                                   const float* __restrict__ wp,
                                                   f16* __restrict__ wTq,
                                                   f16* __restrict__ wTp) {
    int flat = blockIdx.x * 256 + threadIdx.x;
    if (flat < 64 * 1536) {
        int e = flat / 1536, col = flat % 1536;
        int h = col / 192, r = col - h * 192;
        int d = r / 3, c = r - 3 * d;
        int jp = h * 192 + c * 64 + d;
        wTq[(size_t)jp * 64 + e] = (f16)wq[flat];
    } else {
        int f2 = flat - 64 * 1536;
        int k = f2 / 64, n = f2 % 64;
        wTp[(size_t)n * 512 + k] = (f16)wp[f2];
    }
}

// ---------------------------------------------------------------------------
// Kernel 2: QKV projection (MFMA) + LDS-bounce coalesced stores.
// jt 0-3 -> Q (pre-scaled by log2e in fp32), 4-7 -> K, 8-11 -> V.
//   Qb[bh][n][d], Kb[bh][n][d], Vtb[bh][d][n]
// ---------------------------------------------------------------------------
__global__ __launch_bounds__(256) void qkv_kernel(const float* __restrict__ x,
                                                  const f16* __restrict__ wTq,
                                                  const float* __restrict__ b_qkv,
                                                  f16* __restrict__ Qb,
                                                  f16* __restrict__ Kb,
                                                  f16* __restrict__ Vtb) {
    __shared__ __align__(16) char smem[36864];
    f16* xs = (f16*)smem;                  // [64][72]
    f16* wsh = (f16*)(smem + 9216);        // [192][72]
    f16* outs = (f16*)smem;                // [3][64][72]

    const int n0   = blockIdx.x * 64;
    const int y    = blockIdx.y;
    const int b    = y & 31, h = y >> 5;
    const int bh   = b * NH + h;
    const int tid  = threadIdx.x;
    const int wave = tid >> 6, lane = tid & 63;
    const int quad = lane >> 4, l16 = lane & 15;

    for (int p = 0; p < 2; p++) {
        int t = tid + p * 256;
        int row = t >> 3, col = (t & 7) * 8;
        const float* src = x + ((size_t)(b * SEQ + n0 + row)) * 64 + col;
        float4 a0 = *(const float4*)src;
        float4 a1 = *(const float4*)(src + 4);
        f16x8 v = {(f16)a0.x, (f16)a0.y, (f16)a0.z, (f16)a0.w,
                   (f16)a1.x, (f16)a1.y, (f16)a1.z, (f16)a1.w};
        *(f16x8*)(&xs[row * 72 + col]) = v;
    }
    for (int p = 0; p < 6; p++) {
        int row = p * 32 + (tid >> 3), col = (tid & 7) * 8;
        *(f16x8*)(&wsh[row * 72 + col]) =
            *(const f16x8*)(wTq + (size_t)(h * 192 + row) * 64 + col);
    }
    __syncthreads();

    f16x8 af[2];
    af[0] = *(const f16x8*)(&xs[(wave * 16 + l16) * 72 + quad * 8]);
    af[1] = *(const f16x8*)(&xs[(wave * 16 + l16) * 72 + quad * 8 + 32]);

    f32x4 acc[12];
    f32x4 z = {0.f, 0.f, 0.f, 0.f};
    for (int jt = 0; jt < 12; jt++) acc[jt] = z;
    for (int jt = 0; jt < 12; jt++)
        for (int ss = 0; ss < 2; ss++) {
            f16x8 bf = *(const f16x8*)(&wsh[(jt * 16 + l16) * 72 + quad * 8 + ss * 32]);
            acc[jt] = MFMA16(af[ss], bf, acc[jt], 0, 0, 0);
        }

    __syncthreads();   // done reading xs/wsh; reuse as outs

    for (int jt = 0; jt < 12; jt++) {
        int c = jt >> 2, d = (jt & 3) * 16 + l16;
        float bias = b_qkv[h * 192 + d * 3 + c];
        float scl = (c == 0) ? LOG2E : 1.0f;
        for (int r = 0; r < 4; r++) {
            int nl = wave * 16 + quad * 4 + r;
            int off = (c < 2) ? (c * 4608 + nl * 72 + d) : (9216 + d * 72 + nl);
            outs[off] = (f16)((acc[jt][r] + bias) * scl);
        }
    }
    __syncthreads();

    {
        int rr = tid >> 2, ch = (tid & 3) * 16;
        f16x8 v0, v1;
        v0 = *(const f16x8*)(&outs[rr * 72 + ch]);
        v1 = *(const f16x8*)(&outs[rr * 72 + ch + 8]);
        f16* qd = Qb + ((size_t)bh * SEQ + n0 + rr) * HD + ch;
        *(f16x8*)qd = v0; *(f16x8*)(qd + 8) = v1;
        v0 = *(const f16x8*)(&outs[4608 + rr * 72 + ch]);
        v1 = *(const f16x8*)(&outs[4608 + rr * 72 + ch + 8]);
        f16* kd = Kb + ((size_t)bh * SEQ + n0 + rr) * HD + ch;
        *(f16x8*)kd = v0; *(f16x8*)(kd + 8) = v1;
        v0 = *(const f16x8*)(&outs[9216 + rr * 72 + ch]);
        v1 = *(const f16x8*)(&outs[9216 + rr * 72 + ch + 8]);
        f16* vd = Vtb + ((size_t)bh * HD + rr) * SEQ + n0 + ch;
        *(f16x8*)vd = v0; *(f16x8*)(vd + 8) = v1;
    }
}

// ---------------------------------------------------------------------------
// Kernel 3: flash attention (R6 structure + p_lds aliased onto idle kv buf).
//   S^T = K·Q^T (per-lane softmax), O^T = V^T·P^T, 32 qrows/wave.
//   Double-buffered K/V, 1 barrier/kt. P^T lives in the DEAD kv buffer
//   (tile kt-1): wave w's p-slice = alias rows [32w,32w+32) and wave w
//   stages exactly those rows (w0/w1: K rows 0-31/32-63; w2/w3: V rows),
//   so its end-of-kt prefetch store lands only in its own consumed p region.
//   LDS 34816 B -> 4 blocks/CU (16 waves/CU).
// Grid: 2048 blocks XCD-swizzled (qt-siblings of a bh share id%8 -> L2 reuse).
// ---------------------------------------------------------------------------
__global__ __launch_bounds__(256, 4) void flash_kernel(const f16* __restrict__ Qb,
                                                       const f16* __restrict__ Kb,
                                                       const f16* __restrict__ Vtb,
                                                       f16* __restrict__ attn) {
    __shared__ __align__(16) f16 kv[2][2][64 * KST];   // [buf][K/V][row*KST]

    const int id   = blockIdx.x;
    const int xcd  = id & 7;
    const int kk   = id >> 3;
    const int qt   = kk & 7;
    const int bh   = ((kk >> 3) << 3) | xcd;
    const int b    = bh >> 3, h = bh & 7;
    const int tid  = threadIdx.x;
    const int wave = tid >> 6, lane = tid & 63;
    const int quad = lane >> 4, l16 = lane & 15;

    const f16* kg = Kb  + (size_t)bh * SEQ * HD;
    const f16* vg = Vtb + (size_t)bh * HD * SEQ;

    // staging geometry: wave w covers 32 rows (region=K/V, half=row block)
    const int region = wave >> 1;          // 0 = K rows, 1 = V rows
    const int half   = wave & 1;           // rows [32*half, 32*half+32)
    const int lrow   = lane >> 3;          // 0..7
    const int lcol   = (lane & 7) * 8;     // 0..56

    // stage tile 0 into kv[0]
    {
        if (region == 0) {
            for (int p = 0; p < 4; p++) {
                int r = half * 32 + p * 8 + lrow;
                f16x8 v = *(const f16x8*)(kg + (size_t)r * HD + lcol);
                st8(&kv[0][0][r * KST + lcol], v);
            }
        } else {
            for (int p = 0; p < 4; p++) {
                int r = half * 32 + p * 8 + lrow;
                f16x8 v = *(const f16x8*)(vg + (size_t)r * SEQ + lcol);
                st8(&kv[0][1][r * KST + lcol], v);
            }
        }
    }

    // Q fragments (B-operand): lane holds Q[qrow=j*16+l16][d=quad*8+..]
    const f16* Qp = Qb + ((size_t)bh * SEQ + qt * 128 + wave * 32) * HD;
    f16x8 qf[2][2];
    for (int j = 0; j < 2; j++)
        for (int ss = 0; ss < 2; ss++)
            qf[j][ss] = *(const f16x8*)(Qp + (size_t)(j * 16 + l16) * HD + ss * 32 + quad * 8);

    float m_st[2] = {-INFINITY, -INFINITY};
    float l_st[2] = {0.f, 0.f};
    f32x4 o[4][2];
    f32x4 z = {0.f, 0.f, 0.f, 0.f};
    for (int mt = 0; mt < 4; mt++) { o[mt][0] = z; o[mt][1] = z; }

    __syncthreads();

    for (int kt = 0; kt < SEQ / 64; kt++) {
        const int buf = kt & 1;

        // prefetch next tile rows (this wave's 32 assigned rows) into regs
        f16x8 pf[4];
        if (kt < SEQ / 64 - 1) {
            if (region == 0) {
                const f16* g = kg + (size_t)((kt + 1) * 64) * HD;
                for (int p = 0; p < 4; p++) {
                    int r = half * 32 + p * 8 + lrow;
                    pf[p] = *(const f16x8*)(g + (size_t)r * HD + lcol);
                }
            } else {
                const f16* g = vg + (kt + 1) * 64;
                for (int p = 0; p < 4; p++) {
                    int r = half * 32 + p * 8 + lrow;
                    pf[p] = *(const f16x8*)(g + (size_t)r * SEQ + lcol);
                }
            }
        }

        const f16* ks = &kv[buf][0][0];
        const f16* vs = &kv[buf][1][0];
        f16* pw = &kv[buf ^ 1][0][0] + (wave * 2) * 16 * KST;   // p-slice [2][16][KST]

        // ---- S^T = K · Q^T ----
        f32x4 s[4][2];
        for (int ct = 0; ct < 4; ct++) {
            f16x8 ka = ld8(ks + (ct * 16 + l16) * KST + quad * 8);
            f16x8 kc = ld8(ks + (ct * 16 + l16) * KST + quad * 8 + 32);
            s[ct][0] = MFMA16(ka, qf[0][0], z, 0, 0, 0);
            s[ct][0] = MFMA16(kc, qf[0][1], s[ct][0], 0, 0, 0);
            s[ct][1] = MFMA16(ka, qf[1][0], z, 0, 0, 0);
            s[ct][1] = MFMA16(kc, qf[1][1], s[ct][1], 0, 0, 0);
        }

        // ---- online softmax, exp2 domain ----
        for (int j = 0; j < 2; j++) {
            float mx = fmaxf(fmaxf(fmaxf(s[0][j][0], s[0][j][1]), fmaxf(s[0][j][2], s[0][j][3])),
                             fmaxf(fmaxf(s[1][j][0], s[1][j][1]), fmaxf(s[1][j][2], s[1][j][3])));
            mx = fmaxf(mx, fmaxf(fmaxf(fmaxf(s[2][j][0], s[2][j][1]), fmaxf(s[2][j][2], s[2][j][3])),
                                 fmaxf(fmaxf(s[3][j][0], s[3][j][1]), fmaxf(s[3][j][2], s[3][j][3]))));
            mx = fmaxf(mx, __shfl_xor(mx, 16, 64));
            mx = fmaxf(mx, __shfl_xor(mx, 32, 64));
            float mn = fmaxf(m_st[j], mx);
            float al = EXP2F(m_st[j] - mn);
            m_st[j] = mn;
            float rs = 0.f;
            for (int ct = 0; ct < 4; ct++)
                for (int r = 0; r < 4; r++) {
                    float p = EXP2F(s[ct][j][r] - mn);
                    s[ct][j][r] = p;
                    rs += p;
                }
            rs += __shfl_xor(rs, 16, 64);
            rs += __shfl_xor(rs, 32, 64);
            l_st[j] = l_st[j] * al + rs;
            if (!__all(al >= 1.0f))                    // wave-uniform skip
                for (int mt = 0; mt < 4; mt++) o[mt][j] *= al;

            // P^T -> aliased p-slice (packed cvt, b64 writes, bank-even)
            for (int ct = 0; ct < 4; ct++) {
                h16x2 lo = __builtin_amdgcn_cvt_pkrtz(s[ct][j][0], s[ct][j][1]);
                h16x2 hi = __builtin_amdgcn_cvt_pkrtz(s[ct][j][2], s[ct][j][3]);
                uint2 w = {__builtin_bit_cast(unsigned int, lo),
                           __builtin_bit_cast(unsigned int, hi)};
                *(uint2*)(pw + (j * 16 + l16) * KST + ct * 16 + quad * 4) = w;
            }
        }

        __asm__ volatile("s_waitcnt lgkmcnt(0)" ::: "memory");

        // ---- O^T += V^T · P^T ----
        {
            f16x8 va[4];
            for (int mt = 0; mt < 4; mt++)
                va[mt] = ld8(vs + (mt * 16 + l16) * KST + quad * 8);
            f16x8 p0 = ld8(pw + l16 * KST + quad * 8);
            f16x8 p1 = ld8(pw + (16 + l16) * KST + quad * 8);
            for (int mt = 0; mt < 4; mt++) {
                o[mt][0] = MFMA16(va[mt], p0, o[mt][0], 0, 0, 0);
                o[mt][1] = MFMA16(va[mt], p1, o[mt][1], 0, 0, 0);
            }
            for (int mt = 0; mt < 4; mt++)
                va[mt] = ld8(vs + (mt * 16 + l16) * KST + quad * 8 + 32);
            p0 = ld8(pw + l16 * KST + quad * 8 + 32);
            p1 = ld8(pw + (16 + l16) * KST + quad * 8 + 32);
            for (int mt = 0; mt < 4; mt++) {
                o[mt][0] = MFMA16(va[mt], p0, o[mt][0], 0, 0, 0);
                o[mt][1] = MFMA16(va[mt], p1, o[mt][1], 0, 0, 0);
            }
        }

        // write prefetched rows into this wave's own (consumed) p-slice region
        if (kt < SEQ / 64 - 1) {
            f16* dst = &kv[buf ^ 1][region][0];
            for (int p = 0; p < 4; p++) {
                int r = half * 32 + p * 8 + lrow;
                st8(dst + r * KST + lcol, pf[p]);
            }
        }
        __syncthreads();
    }

    // epilogue: attn[b][n][h*64+d], post-softmax /8 folded in
    for (int j = 0; j < 2; j++) {
        float sc = 1.0f / (8.0f * l_st[j]);
        int n = qt * 128 + wave * 32 + j * 16 + l16;
        f16* op = attn + ((size_t)b * SEQ + n) * HID + h * HD + quad * 4;
        for (int mt = 0; mt < 4; mt++) {
            f16x4 w = {(f16)(o[mt][j][0] * sc), (f16)(o[mt][j][1] * sc),
                       (f16)(o[mt][j][2] * sc), (f16)(o[mt][j][3] * sc)};
            *(f16x4*)(op + mt * 16) = w;
        }
    }
}

// ---------------------------------------------------------------------------
// Kernel 4: output projection. attn (32768 x 512) @ w_proj (512 x 64) + b.
// ---------------------------------------------------------------------------
__global__ __launch_bounds__(256) void proj_kernel(const f16* __restrict__ attn,
                                                   const f16* __restrict__ wTp,
                                                   const float* __restrict__ b_proj,
                                                   float* __restrict__ out) {
    __shared__ __align__(16) f16 a_lds[64][72];
    __shared__ __align__(16) f16 w_lds[64][72];

    const int blk  = blockIdx.x;
    const int tid  = threadIdx.x;
    const int wave = tid >> 6, lane = tid & 63;
    const int quad = lane >> 4, l16 = lane & 15;

    f32x4 acc[4];
    f32x4 z = {0.f, 0.f, 0.f, 0.f};
    for (int ct = 0; ct < 4; ct++) acc[ct] = z;

    for (int kt = 0; kt < 8; kt++) {
        __syncthreads();
        for (int p = 0; p < 2; p++) {
            int t = tid + p * 256;
            int row = t >> 3, col = (t & 7) * 8;
            *(f16x8*)(&a_lds[row][col]) =
                *(const f16x8*)(attn + ((size_t)(blk * 64 + row)) * HID + kt * 64 + col);
            *(f16x8*)(&w_lds[row][col]) =
                *(const f16x8*)(wTp + (size_t)row * HID + kt * 64 + col);
        }
        __syncthreads();
        for (int ss = 0; ss < 2; ss++) {
            f16x8 af = *(const f16x8*)(&a_lds[wave * 16 + l16][quad * 8 + ss * 32]);
            for (int ct = 0; ct < 4; ct++) {
                f16x8 bf = *(const f16x8*)(&w_lds[ct * 16 + l16][quad * 8 + ss * 32]);
                acc[ct] = MFMA16(af, bf, acc[ct], 0, 0, 0);
            }
        }
    }

    for (int ct = 0; ct < 4; ct++) {
        float bias = b_proj[ct * 16 + l16];
        for (int r = 0; r < 4; r++) {
            int row = blk * 64 + wave * 16 + quad * 4 + r;
            out[(size_t)row * HD + ct * 16 + l16] = acc[ct][r] + bias;
        }
    }
}

// ---------------------------------------------------------------------------
extern "C" void kernel_launch(void* const* d_in, const int* in_sizes, int n_in,
                              void* d_out, int out_size, void* d_ws, size_t ws_size,
                              hipStream_t stream) {
    (void)in_sizes; (void)n_in; (void)out_size; (void)ws_size;
    const float* x      = (const float*)d_in[0];
    const float* w_qkv  = (const float*)d_in[1];
    const float* b_qkv  = (const float*)d_in[2];
    const float* w_proj = (const float*)d_in[3];
    const float* b_proj = (const float*)d_in[4];
    float* out = (float*)d_out;

    char* ws = (char*)d_ws;
    const size_t QKV_EL = (size_t)BATCH * NH * SEQ * HD;
    f16* wTq  = (f16*)(ws);
    f16* wTp  = (f16*)(ws + 196608);
    f16* Qb   = (f16*)(ws + 262144);
    f16* Kb   = (f16*)(ws + 262144 + 2 * QKV_EL);
    f16* Vtb  = (f16*)(ws + 262144 + 4 * QKV_EL);
    f16* attn = (f16*)(ws + 262144 + 6 * QKV_EL);

    transpose_w<<<512, 256, 0, stream>>>(w_qkv, w_proj, wTq, wTp);
    qkv_kernel<<<dim3(16, BATCH * NH), 256, 0, stream>>>(x, wTq, b_qkv, Qb, Kb, Vtb);
    flash_kernel<<<2048, 256, 0, stream>>>(Qb, Kb, Vtb, attn);
    proj_kernel<<<512, 256, 0, stream>>>(attn, wTp, b_proj, out);
}